// Round 4
// baseline (707.096 us; speedup 1.0000x reference)
//
#include <hip/hip_runtime.h>
#include <hip/hip_bf16.h>
#include <math.h>

// ---------------------------------------------------------------------------
// VAR quantizer forward. Round 4: k_nn prefetch-depth-2 (triple-buffered LDS,
// counted vmcnt) + 3-4 blocks/CU; fully fused per-scale k_fuse
// (combine+gather+bicubic+DPP-conv+loss+residual+pool). 22 dispatches.
// All NN/conv arithmetic bitwise-identical to the passing round-3 kernel.
// Output: [f_hat 1048576][loss 1][idx-as-float 87040]
// ---------------------------------------------------------------------------

#define B_  128
#define V_  4096
#define SN_ 10
#define NPIX_ (B_*32*256)   // 1048576

// ws layout (float offsets)
#define WS_FREST   0
#define WS_FHAT    1048576
#define WS_PD      2097152
#define WS_PI      2359296
#define WS_ESQ     2621440
#define WS_TW      2625536
#define WS_TI      2626112
#define WS_LOSSP   2626688
#define WS_RESTH   2629248
#define WS_RESTM   3153536
#define WS_RESTL   3677824
#define WS_EMBH    4202112
#define WS_EMBM    4267648
#define WS_EMBL    4333184
// end 4398720 floats = 16.8 MB

typedef __attribute__((ext_vector_type(8))) short short8_t;
typedef __attribute__((ext_vector_type(4))) float f32x4;
#define MFMA(a,b,c) __builtin_amdgcn_mfma_f32_16x16x32_bf16((a),(b),(c),0,0,0)

__device__ inline void gl_lds16(const void* g, void* l) {
  __builtin_amdgcn_global_load_lds((const __attribute__((address_space(1))) void*)g,
                                   (__attribute__((address_space(3))) void*)l, 16, 0, 0);
}
__device__ inline void gl_lds4(const void* g, void* l) {
  __builtin_amdgcn_global_load_lds((const __attribute__((address_space(1))) void*)g,
                                   (__attribute__((address_space(3))) void*)l, 4, 0, 0);
}

// split f32 -> 3 truncated bf16 levels (captures ~24 bits)
__device__ inline void split3(float a, ushort* h, ushort* m, ushort* l) {
  unsigned ua = __float_as_uint(a);
  ushort uh = (ushort)(ua >> 16);
  float fh = __uint_as_float((unsigned)uh << 16);
  float r1 = a - fh;
  ushort um = (ushort)(__float_as_uint(r1) >> 16);
  float fm = __uint_as_float((unsigned)um << 16);
  float r2 = r1 - fm;
  ushort ul = (ushort)(__float_as_uint(r2) >> 16);
  *h = uh; *m = um; *l = ul;
}

// DPP lane shifts within 16-lane rows; bound_ctrl=1 -> zero fill (SAME pad)
__device__ inline float dpp_shr1(float x) {  // value from lane-1 (X-1)
  return __uint_as_float(__builtin_amdgcn_update_dpp(0u, __float_as_uint(x),
                                                     0x111, 0xF, 0xF, true));
}
__device__ inline float dpp_shl1(float x) {  // value from lane+1 (X+1)
  return __uint_as_float(__builtin_amdgcn_update_dpp(0u, __float_as_uint(x),
                                                     0x101, 0xF, 0xF, true));
}

// --------------------------- prep kernel (3 roles) --------------------------

__global__ __launch_bounds__(256) void k_prep(const float* __restrict__ emb,
                                              const float* __restrict__ f,
                                              float* __restrict__ esq,
                                              ushort* __restrict__ eh,
                                              ushort* __restrict__ em,
                                              ushort* __restrict__ el,
                                              float* __restrict__ tw,
                                              int* __restrict__ ti,
                                              ushort* __restrict__ rh,
                                              ushort* __restrict__ rm,
                                              ushort* __restrict__ rl) {
  int bx = blockIdx.x, t = threadIdx.x;
  if (bx < 16) {
    // emb split + (-esq/2)
    int v = bx * 256 + t;
    const float4* e4 = (const float4*)(emb + (size_t)v * 32);
    float s = 0.f;
#pragma unroll
    for (int half = 0; half < 4; ++half) {
      float4 x0 = e4[half * 2], x1 = e4[half * 2 + 1];
      s += x0.x * x0.x + x0.y * x0.y + x0.z * x0.z + x0.w * x0.w;
      s += x1.x * x1.x + x1.y * x1.y + x1.z * x1.z + x1.w * x1.w;
      float xs[8] = {x0.x, x0.y, x0.z, x0.w, x1.x, x1.y, x1.z, x1.w};
      ushort hs[8], ms[8], ls[8];
#pragma unroll
      for (int j = 0; j < 8; ++j) split3(xs[j], &hs[j], &ms[j], &ls[j]);
      uint4 ph, pm, pl;
      ph.x = (unsigned)hs[0] | ((unsigned)hs[1] << 16); ph.y = (unsigned)hs[2] | ((unsigned)hs[3] << 16);
      ph.z = (unsigned)hs[4] | ((unsigned)hs[5] << 16); ph.w = (unsigned)hs[6] | ((unsigned)hs[7] << 16);
      pm.x = (unsigned)ms[0] | ((unsigned)ms[1] << 16); pm.y = (unsigned)ms[2] | ((unsigned)ms[3] << 16);
      pm.z = (unsigned)ms[4] | ((unsigned)ms[5] << 16); pm.w = (unsigned)ms[6] | ((unsigned)ms[7] << 16);
      pl.x = (unsigned)ls[0] | ((unsigned)ls[1] << 16); pl.y = (unsigned)ls[2] | ((unsigned)ls[3] << 16);
      pl.z = (unsigned)ls[4] | ((unsigned)ls[5] << 16); pl.w = (unsigned)ls[6] | ((unsigned)ls[7] << 16);
      ((uint4*)(eh + (size_t)v * 32))[half] = ph;
      ((uint4*)(em + (size_t)v * 32))[half] = pm;
      ((uint4*)(el + (size_t)v * 32))[half] = pl;
    }
    esq[v] = -0.5f * s;
  } else if (bx == 16) {
    // bicubic tap tables (f64, matches numpy)
    if (t >= 144) return;
    const int pns[9] = {1, 2, 3, 4, 5, 6, 8, 10, 13};
    int si = t / 16, Y = t % 16;
    int pn = pns[si];
    double src = (Y + 0.5) * (double)pn / 16.0 - 0.5;
    double fl = floor(src);
    const double a = -0.75;
#pragma unroll
    for (int k = 0; k < 4; ++k) {
      double x = fabs(src - (fl + (k - 1)));
      double w;
      if (x <= 1.0)      w = (a + 2.0) * x * x * x - (a + 3.0) * x * x + 1.0;
      else if (x < 2.0)  w = a * x * x * x - 5.0 * a * x * x + 8.0 * a * x - 4.0 * a;
      else               w = 0.0;
      int id = (int)fl + (k - 1);
      id = id < 0 ? 0 : (id > pn - 1 ? pn - 1 : id);
      tw[si * 64 + Y * 4 + k] = (float)w;
      ti[si * 64 + Y * 4 + k] = id;
    }
  } else {
    // si=0 NN input: area-pool f to 1x1 -> [n][c] 3-level bf16
    int tid = (bx - 17) * 256 + t;     // 4096 total
    int c = tid & 31, n = tid >> 5;
    const float* base = f + ((size_t)n * 32 + c) * 256;
    float s = 0.f;
    for (int yy = 0; yy < 16; ++yy)
      for (int xx = 0; xx < 16; ++xx) s += base[yy * 16 + xx];
    float a = s * ((1.0f / 16.0f) * (1.0f / 16.0f));
    ushort uh, um, ul;
    split3(a, &uh, &um, &ul);
    rh[(size_t)n * 32 + c] = uh;
    rm[(size_t)n * 32 + c] = um;
    rl[(size_t)n * 32 + c] = ul;
  }
}

// --------------------------- NN search -------------------------------------
// Block: 4 waves x R row-tiles of 16 rows vs 64-code tiles. Triple-buffered
// emb staging, prefetch depth 2, counted vmcnt. Maximizes dot - esq/2.
template<int R>
__global__ __launch_bounds__(256) void k_nn(const ushort* __restrict__ rest_h,
                                            const ushort* __restrict__ rest_m,
                                            const ushort* __restrict__ rest_l,
                                            const ushort* __restrict__ emb_h,
                                            const ushort* __restrict__ emb_m,
                                            const ushort* __restrict__ emb_l,
                                            const float* __restrict__ esq_g,
                                            float* __restrict__ pdist,
                                            int* __restrict__ pidx,
                                            int rows, int S, int cps) {
  __shared__ ushort lb[3][3][2048];
  __shared__ float les[3][64];
  const int t = threadIdx.x;
  const int w = t >> 6;
  const int col = t & 15;
  const int g = (t >> 4) & 3;
  const int sp = blockIdx.y;
  const int rowbase = blockIdx.x * (64 * R);

  auto stage = [&](int bf, int ch) {
    int cb = sp * cps + ch * 64;
    int code = cb + (t >> 2);
    int u = (t & 3) ^ ((code ^ (code >> 2)) & 3);
    size_t off = (size_t)code * 32 + (size_t)u * 8;
    gl_lds16(emb_h + off, &lb[bf][0][w * 512]);
    gl_lds16(emb_m + off, &lb[bf][1][w * 512]);
    gl_lds16(emb_l + off, &lb[bf][2][w * 512]);
    if ((t & 63) < 16) gl_lds4(esq_g + cb + w * 16 + (t & 15), &les[bf][w * 16]);
  };

  const int NC = cps >> 6;
  stage(0, 0);

  // A fragments in registers (3 levels x R row-tiles)
  short8_t ah[R], am[R], al[R];
#pragma unroll
  for (int rt = 0; rt < R; ++rt) {
    int n = rowbase + (w * R + rt) * 16 + col;
    if (n >= rows) n = rows - 1;
    size_t o = (size_t)n * 32 + g * 8;
    ah[rt] = *(const short8_t*)(rest_h + o);
    am[rt] = *(const short8_t*)(rest_m + o);
    al[rt] = *(const short8_t*)(rest_l + o);
  }

  if (NC > 1) stage(1, 1);

  float best[R][4];
  int bidx[R][4];
#pragma unroll
  for (int rt = 0; rt < R; ++rt)
#pragma unroll
    for (int r = 0; r < 4; ++r) { best[rt][r] = -3.4e38f; bidx[rt][r] = 0x7fffffff; }

  int buf = 0;
  for (int ch = 0; ch < NC; ++ch) {
    if (ch + 2 < NC) {
      stage((ch + 2) % 3, ch + 2);
      asm volatile("s_waitcnt vmcnt(8)" ::: "memory");
    } else if (ch + 1 < NC) {
      asm volatile("s_waitcnt vmcnt(4)" ::: "memory");
    } else {
      asm volatile("s_waitcnt vmcnt(0)" ::: "memory");
    }
    __builtin_amdgcn_s_barrier();

    int cb0 = sp * cps + ch * 64;
#pragma unroll
    for (int s4 = 0; s4 < 4; ++s4) {
      int cl = s4 * 16 + col;
      int slotbase = (cl * 4 + (g ^ ((cl ^ (cl >> 2)) & 3))) * 8;
      short8_t bh  = *(const short8_t*)&lb[buf][0][slotbase];
      short8_t bm  = *(const short8_t*)&lb[buf][1][slotbase];
      short8_t bl2 = *(const short8_t*)&lb[buf][2][slotbase];
      float es = les[buf][cl];
      f32x4 c0 = {es, es, es, es};
      f32x4 acc[R];
      // per-acc order identical to rounds 2-3: hh,hm,mh,hl,mm,lh
#pragma unroll
      for (int rt = 0; rt < R; ++rt) acc[rt] = MFMA(ah[rt], bh, c0);
#pragma unroll
      for (int rt = 0; rt < R; ++rt) acc[rt] = MFMA(ah[rt], bm, acc[rt]);
#pragma unroll
      for (int rt = 0; rt < R; ++rt) acc[rt] = MFMA(am[rt], bh, acc[rt]);
#pragma unroll
      for (int rt = 0; rt < R; ++rt) acc[rt] = MFMA(ah[rt], bl2, acc[rt]);
#pragma unroll
      for (int rt = 0; rt < R; ++rt) acc[rt] = MFMA(am[rt], bm, acc[rt]);
#pragma unroll
      for (int rt = 0; rt < R; ++rt) acc[rt] = MFMA(al[rt], bh, acc[rt]);
      int code = cb0 + cl;
#pragma unroll
      for (int rt = 0; rt < R; ++rt)
#pragma unroll
        for (int r = 0; r < 4; ++r)
          if (acc[rt][r] > best[rt][r]) { best[rt][r] = acc[rt][r]; bidx[rt][r] = code; }
    }
    __syncthreads();
    buf = (buf + 1) % 3;
  }

#pragma unroll
  for (int rt = 0; rt < R; ++rt)
#pragma unroll
    for (int r = 0; r < 4; ++r) {
      float bd = best[rt][r];
      int bi = bidx[rt][r];
#pragma unroll
      for (int mm2 = 1; mm2 < 16; mm2 <<= 1) {
        float od = __shfl_xor(bd, mm2, 16);
        int oi = __shfl_xor(bi, mm2, 16);
        if (od > bd || (od == bd && oi < bi)) { bd = od; bi = oi; }
      }
      if ((t & 15) == 0) {
        int rown = rowbase + (w * R + rt) * 16 + g * 4 + r;
        if (rown < rows) {
          pdist[(size_t)rown * S + sp] = bd;
          pidx[(size_t)rown * S + sp] = bi;
        }
      }
    }
}

// --------------------------- fused per-scale kernel -------------------------
// grid (B,2), 256 thr, 16 out-ch per block, 1 block/CU.
__global__ __launch_bounds__(256) void k_fuse(const float* __restrict__ pdist,
                                              const int* __restrict__ pidx,
                                              const float* __restrict__ emb,
                                              const float* __restrict__ tw,
                                              const int* __restrict__ ti,
                                              const float* __restrict__ W,
                                              const float* __restrict__ bias,
                                              const float* __restrict__ f,
                                              const float* __restrict__ frest_in,
                                              const float* __restrict__ fhat_in,
                                              float* __restrict__ fhat_out,
                                              float* __restrict__ frest_out,
                                              float* __restrict__ out_idx_f,
                                              float* __restrict__ lossp,
                                              ushort* __restrict__ rh,
                                              ushort* __restrict__ rm,
                                              ushort* __restrict__ rl,
                                              int S, int pn, int si, int pn_next) {
  __shared__ float in_s[32 * 256];
  __shared__ float hsm[32 * 176];
  __shared__ float xt[32 * 208];
  __shared__ int   ci_s[256];
  __shared__ float red[256];
  const int b = blockIdx.x;
  const int cog = blockIdx.y * 16;
  const int t = threadIdx.x;
  const int pn2 = pn * pn;
  const bool last = (si == SN_ - 1);

  // ---- combine NN split-partials -> codes (+ write idx output)
  for (int rem = t; rem < pn2; rem += 256) {
    const float* pd = pdist + (size_t)(b * pn2 + rem) * S;
    const int* pi = pidx + (size_t)(b * pn2 + rem) * S;
    float bd = pd[0]; int bi = pi[0];
    for (int s = 1; s < S; ++s) {
      float d = pd[s]; int i2 = pi[s];
      if (d > bd || (d == bd && i2 < bi)) { bd = d; bi = i2; }
    }
    ci_s[rem] = bi;
    out_idx_f[b * pn2 + rem] = (float)bi;
  }
  __syncthreads();

  if (last) {
    // gather emb rows straight into conv input
    int code = ci_s[t];
    const float4* er = (const float4*)(emb + (size_t)code * 32);
#pragma unroll
    for (int q = 0; q < 8; ++q) {
      float4 e = er[q];
      in_s[(q * 4 + 0) * 256 + t] = e.x;
      in_s[(q * 4 + 1) * 256 + t] = e.y;
      in_s[(q * 4 + 2) * 256 + t] = e.z;
      in_s[(q * 4 + 3) * 256 + t] = e.w;
    }
    __syncthreads();
  } else {
    {
      int c = t & 31;
      for (int r0 = t >> 5; r0 < pn2; r0 += 8)
        hsm[c * 176 + r0] = emb[(size_t)ci_s[r0] * 32 + c];
    }
    __syncthreads();
    // separable bicubic: stage 1 (x-interp), stage 2 (y-interp)
    {
      int X = t & 15;
      float wx[4]; int ixx[4];
#pragma unroll
      for (int u = 0; u < 4; ++u) { wx[u] = tw[si * 64 + X * 4 + u]; ixx[u] = ti[si * 64 + X * 4 + u]; }
      int e1 = 32 * pn * 16;
      for (int i = t; i < e1; i += 256) {
        int r2 = i >> 4;
        int y = r2 % pn, c = r2 / pn;
        const float* hr = &hsm[c * 176 + y * pn];
        float a = 0.f;
#pragma unroll
        for (int u = 0; u < 4; ++u) a += wx[u] * hr[ixx[u]];
        xt[c * 208 + y * 16 + X] = a;
      }
    }
    __syncthreads();
    {
      int X = t & 15, Y = t >> 4;
      float wy[4]; int iy[4];
#pragma unroll
      for (int u = 0; u < 4; ++u) { wy[u] = tw[si * 64 + Y * 4 + u]; iy[u] = ti[si * 64 + Y * 4 + u]; }
      for (int c = 0; c < 32; ++c) {
        float a = 0.f;
#pragma unroll
        for (int u = 0; u < 4; ++u) a += wy[u] * xt[c * 208 + iy[u] * 16 + X];
        in_s[c * 256 + t] = a;
      }
    }
    __syncthreads();
  }

  // ---- 3x3 conv, 16 out-channels, DPP x-neighbors, scalar weights
  float acc[16];
  {
    int bb = __builtin_amdgcn_readfirstlane(cog);
#pragma unroll
    for (int o = 0; o < 16; ++o) acc[o] = bias[bb + o];
  }
  const int Y = t >> 4;
  const bool yup = (Y > 0), ydn = (Y < 15);
  const int om = yup ? -16 : 0, op = ydn ? 16 : 0;
  for (int ci = 0; ci < 32; ++ci) {
    int wb = __builtin_amdgcn_readfirstlane((cog * 32 + ci) * 9);
    float r0 = in_s[ci * 256 + t];
    float rm1 = in_s[ci * 256 + t + om]; if (!yup) rm1 = 0.f;
    float rp1 = in_s[ci * 256 + t + op]; if (!ydn) rp1 = 0.f;
    float in9[9];
    in9[0] = dpp_shr1(rm1); in9[1] = rm1; in9[2] = dpp_shl1(rm1);
    in9[3] = dpp_shr1(r0);  in9[4] = r0;  in9[5] = dpp_shl1(r0);
    in9[6] = dpp_shr1(rp1); in9[7] = rp1; in9[8] = dpp_shl1(rp1);
#pragma unroll
    for (int o = 0; o < 16; ++o) {
      const float* w9 = W + wb + (size_t)o * 288;
#pragma unroll
      for (int q = 0; q < 9; ++q) acc[o] += w9[q] * in9[q];
    }
  }

  // ---- epilogue: residual mix, f_hat/f_rest, loss partial
  float lsum = 0.f;
  float nr[16];
#pragma unroll
  for (int o = 0; o < 16; ++o) {
    size_t oidx = ((size_t)b * 32 + cog + o) * 256 + t;
    float outv = 0.5f * in_s[(cog + o) * 256 + t] + 0.5f * acc[o];
    float prev = fhat_in ? fhat_in[oidx] : 0.f;
    float nf = prev + outv;
    fhat_out[oidx] = nf;
    if (!last) {
      float fr = frest_in[oidx] - outv;
      frest_out[oidx] = fr;
      nr[o] = fr;
    }
    float d = nf - f[oidx];
    lsum += d * d;
  }
  red[t] = lsum;
  __syncthreads();
  for (int o = 128; o > 0; o >>= 1) {
    if (t < o) red[t] += red[t + o];
    __syncthreads();
  }
  if (t == 0) lossp[si * 256 + blockIdx.y * 128 + b] = red[0];

  // ---- pool updated residual for next scale's NN input
  if (!last) {
    __syncthreads();
#pragma unroll
    for (int o = 0; o < 16; ++o) xt[o * 256 + t] = nr[o];
    __syncthreads();
    int pn2n = pn_next * pn_next;
    for (int i = t; i < 16 * pn2n; i += 256) {
      int o = i / pn2n, rem = i - o * pn2n;
      int y = rem / pn_next, x = rem - y * pn_next;
      int sy = (y * 16) / pn_next, ey = ((y + 1) * 16 + pn_next - 1) / pn_next;
      int sx = (x * 16) / pn_next, ex = ((x + 1) * 16 + pn_next - 1) / pn_next;
      float s = 0.f;
      for (int yy = sy; yy < ey; ++yy)
        for (int xx = sx; xx < ex; ++xx) s += xt[o * 256 + yy * 16 + xx];
      float a = s * ((1.0f / (float)(ey - sy)) * (1.0f / (float)(ex - sx)));
      ushort uh, um, ul;
      split3(a, &uh, &um, &ul);
      size_t n = (size_t)b * pn2n + rem;
      rh[n * 32 + cog + o] = uh;
      rm[n * 32 + cog + o] = um;
      rl[n * 32 + cog + o] = ul;
    }
  }
}

__global__ __launch_bounds__(256) void k_lossfin(const float* __restrict__ part,
                                                 float* __restrict__ out) {
  int t = threadIdx.x;
  float s = 0.f;
  for (int i = t; i < SN_ * 256; i += 256) s += part[i];
  __shared__ float red[256];
  red[t] = s;
  __syncthreads();
  for (int o = 128; o > 0; o >>= 1) {
    if (t < o) red[t] += red[t + o];
    __syncthreads();
  }
  if (t == 0) out[NPIX_] = red[0] * (1.25f / (10.0f * (float)NPIX_));
}

// --------------------------- host side -------------------------------------

static void compute_phi_k(int* ks) {
  const int K = 4;
  double start = 1.0 / (3.0 * K);
  double stop = 1.0 - 1.0 / (3.0 * K);
  double step = (stop - start) / (K - 1);
  double ticks[4];
  for (int i = 0; i < K; ++i) ticks[i] = (double)i * step + start;
  ticks[K - 1] = stop;
  for (int si = 0; si < SN_; ++si) {
    double x = (double)si / (SN_ - 1);
    int best = 0;
    double bd = fabs(ticks[0] - x);
    for (int i = 1; i < K; ++i) {
      double d = fabs(ticks[i] - x);
      if (d < bd) { bd = d; best = i; }
    }
    ks[si] = best;
  }
}

extern "C" void kernel_launch(void* const* d_in, const int* in_sizes, int n_in,
                              void* d_out, int out_size, void* d_ws, size_t ws_size,
                              hipStream_t stream) {
  (void)in_sizes; (void)n_in; (void)out_size; (void)ws_size;
  const float* f    = (const float*)d_in[0];
  const float* emb  = (const float*)d_in[1];
  const float* phiW = (const float*)d_in[2];
  const float* phiB = (const float*)d_in[3];
  float* out = (float*)d_out;
  float* ws = (float*)d_ws;

  float* f_rest = ws + WS_FREST;
  float* f_hat  = ws + WS_FHAT;
  float* pdist  = ws + WS_PD;
  int*   pidx   = (int*)(ws + WS_PI);
  float* esq    = ws + WS_ESQ;
  float* tw     = ws + WS_TW;
  int*   ti     = (int*)(ws + WS_TI);
  float* lossp  = ws + WS_LOSSP;
  ushort* rest_h = (ushort*)(ws + WS_RESTH);
  ushort* rest_m = (ushort*)(ws + WS_RESTM);
  ushort* rest_l = (ushort*)(ws + WS_RESTL);
  ushort* emb_h  = (ushort*)(ws + WS_EMBH);
  ushort* emb_m  = (ushort*)(ws + WS_EMBM);
  ushort* emb_l  = (ushort*)(ws + WS_EMBL);

  static const int pns[SN_] = {1, 2, 3, 4, 5, 6, 8, 10, 13, 16};
  static const int Rs[SN_]  = {1, 1, 1, 2, 2, 2, 4, 4, 4, 4};
  static const int Ss[SN_]  = {64, 64, 32, 32, 32, 16, 16, 16, 8, 8};
  int ks[SN_];
  compute_phi_k(ks);

  k_prep<<<33, 256, 0, stream>>>(emb, f, esq, emb_h, emb_m, emb_l, tw, ti,
                                 rest_h, rest_m, rest_l);

  int idx_off = 0;
  for (int si = 0; si < SN_; ++si) {
    int pn = pns[si];
    int pn2 = pn * pn;
    int rows = B_ * pn2;
    int R = Rs[si], S = Ss[si];
    int cps = V_ / S;
    int rowblocks = (rows + 64 * R - 1) / (64 * R);

    dim3 grid(rowblocks, S);
    if (R == 1)
      k_nn<1><<<grid, 256, 0, stream>>>(rest_h, rest_m, rest_l, emb_h, emb_m, emb_l,
                                        esq, pdist, pidx, rows, S, cps);
    else if (R == 2)
      k_nn<2><<<grid, 256, 0, stream>>>(rest_h, rest_m, rest_l, emb_h, emb_m, emb_l,
                                        esq, pdist, pidx, rows, S, cps);
    else
      k_nn<4><<<grid, 256, 0, stream>>>(rest_h, rest_m, rest_l, emb_h, emb_m, emb_l,
                                        esq, pdist, pidx, rows, S, cps);

    bool last = (si == SN_ - 1);
    int pn_next = last ? 0 : pns[si + 1];
    k_fuse<<<dim3(B_, 2), 256, 0, stream>>>(
        pdist, pidx, emb, tw, ti,
        phiW + (size_t)ks[si] * 32 * 32 * 9, phiB + (size_t)ks[si] * 32,
        f,
        (si == 0) ? f : f_rest,                    // frest_in
        (si == 0) ? (const float*)nullptr : f_hat, // fhat_in
        last ? out : f_hat,                        // fhat_out
        last ? (float*)nullptr : f_rest,           // frest_out
        out + NPIX_ + 1 + idx_off, lossp,
        rest_h, rest_m, rest_l,
        S, pn, si, pn_next);
    idx_off += rows;
  }

  k_lossfin<<<1, 256, 0, stream>>>(lossp, out);
}

// Round 5
// 425.260 us; speedup vs baseline: 1.6627x; 1.6627x over previous
//
#include <hip/hip_runtime.h>
#include <hip/hip_bf16.h>
#include <math.h>

// ---------------------------------------------------------------------------
// VAR quantizer forward. Round 5: drop f_hat tracking (f_hat = f - f_rest at
// end; loss = sum(f_rest^2)); MFMA 3x3 conv via 9 shift-GEMMs with 3-level
// bf16 split (same accuracy class as the NN path); DPP lane-shift for dx taps;
// 512-thread k_scale with prefetched f_rest RMW. 22 dispatches.
// Output: [f_hat 1048576][loss 1][idx-as-float 87040]
// ---------------------------------------------------------------------------

#define B_  128
#define V_  4096
#define SN_ 10
#define NPIX_ (B_*32*256)   // 1048576

// ws layout (float offsets)
#define WS_FREST   0
#define WS_PD      1048576
#define WS_PI      1310720
#define WS_ESQ     1572864
#define WS_TW      1576960
#define WS_TI      1577536
#define WS_LOSSP   1578112
#define WS_RESTH   1580672
#define WS_RESTM   2104960
#define WS_RESTL   2629248
#define WS_EMBH    3153536
#define WS_EMBM    3219072
#define WS_EMBL    3284608
#define WS_WSPL    3350144
// end 3405440 floats = 13.6 MB

typedef __attribute__((ext_vector_type(8))) short short8_t;
typedef __attribute__((ext_vector_type(4))) float f32x4;
#define MFMA(a,b,c) __builtin_amdgcn_mfma_f32_16x16x32_bf16((a),(b),(c),0,0,0)

__device__ inline void gl_lds16(const void* g, void* l) {
  __builtin_amdgcn_global_load_lds((const __attribute__((address_space(1))) void*)g,
                                   (__attribute__((address_space(3))) void*)l, 16, 0, 0);
}
__device__ inline void gl_lds4(const void* g, void* l) {
  __builtin_amdgcn_global_load_lds((const __attribute__((address_space(1))) void*)g,
                                   (__attribute__((address_space(3))) void*)l, 4, 0, 0);
}

// split f32 -> 3 truncated bf16 levels (captures ~24 bits)
__device__ inline void split3(float a, ushort* h, ushort* m, ushort* l) {
  unsigned ua = __float_as_uint(a);
  ushort uh = (ushort)(ua >> 16);
  float fh = __uint_as_float((unsigned)uh << 16);
  float r1 = a - fh;
  ushort um = (ushort)(__float_as_uint(r1) >> 16);
  float fm = __uint_as_float((unsigned)um << 16);
  float r2 = r1 - fm;
  ushort ul = (ushort)(__float_as_uint(r2) >> 16);
  *h = uh; *m = um; *l = ul;
}

// DPP lane shifts within 16-lane rows; bound_ctrl=1 -> zero fill (SAME pad)
__device__ inline short8_t s8_from_laneM1(short8_t v) {   // value from lane-1 (X-1)
  union { short8_t s; unsigned u[4]; } a, r;
  a.s = v;
#pragma unroll
  for (int i = 0; i < 4; ++i)
    r.u[i] = __builtin_amdgcn_update_dpp(0u, a.u[i], 0x111, 0xF, 0xF, true);
  return r.s;
}
__device__ inline short8_t s8_from_laneP1(short8_t v) {   // value from lane+1 (X+1)
  union { short8_t s; unsigned u[4]; } a, r;
  a.s = v;
#pragma unroll
  for (int i = 0; i < 4; ++i)
    r.u[i] = __builtin_amdgcn_update_dpp(0u, a.u[i], 0x101, 0xF, 0xF, true);
  return r.s;
}

// --------------------------- prep kernel (4 roles) --------------------------

__global__ __launch_bounds__(256) void k_prep(const float* __restrict__ emb,
                                              const float* __restrict__ f,
                                              const float* __restrict__ phiW,
                                              float* __restrict__ esq,
                                              ushort* __restrict__ eh,
                                              ushort* __restrict__ em,
                                              ushort* __restrict__ el,
                                              float* __restrict__ tw,
                                              int* __restrict__ ti,
                                              ushort* __restrict__ rh,
                                              ushort* __restrict__ rm,
                                              ushort* __restrict__ rl,
                                              ushort* __restrict__ wspl) {
  int bx = blockIdx.x, t = threadIdx.x;
  if (bx < 16) {
    // emb split + (-esq/2)
    int v = bx * 256 + t;
    const float4* e4 = (const float4*)(emb + (size_t)v * 32);
    float s = 0.f;
#pragma unroll
    for (int half = 0; half < 4; ++half) {
      float4 x0 = e4[half * 2], x1 = e4[half * 2 + 1];
      s += x0.x * x0.x + x0.y * x0.y + x0.z * x0.z + x0.w * x0.w;
      s += x1.x * x1.x + x1.y * x1.y + x1.z * x1.z + x1.w * x1.w;
      float xs[8] = {x0.x, x0.y, x0.z, x0.w, x1.x, x1.y, x1.z, x1.w};
      ushort hs[8], ms[8], ls[8];
#pragma unroll
      for (int j = 0; j < 8; ++j) split3(xs[j], &hs[j], &ms[j], &ls[j]);
      uint4 ph, pm, pl;
      ph.x = (unsigned)hs[0] | ((unsigned)hs[1] << 16); ph.y = (unsigned)hs[2] | ((unsigned)hs[3] << 16);
      ph.z = (unsigned)hs[4] | ((unsigned)hs[5] << 16); ph.w = (unsigned)hs[6] | ((unsigned)hs[7] << 16);
      pm.x = (unsigned)ms[0] | ((unsigned)ms[1] << 16); pm.y = (unsigned)ms[2] | ((unsigned)ms[3] << 16);
      pm.z = (unsigned)ms[4] | ((unsigned)ms[5] << 16); pm.w = (unsigned)ms[6] | ((unsigned)ms[7] << 16);
      pl.x = (unsigned)ls[0] | ((unsigned)ls[1] << 16); pl.y = (unsigned)ls[2] | ((unsigned)ls[3] << 16);
      pl.z = (unsigned)ls[4] | ((unsigned)ls[5] << 16); pl.w = (unsigned)ls[6] | ((unsigned)ls[7] << 16);
      ((uint4*)(eh + (size_t)v * 32))[half] = ph;
      ((uint4*)(em + (size_t)v * 32))[half] = pm;
      ((uint4*)(el + (size_t)v * 32))[half] = pl;
    }
    esq[v] = -0.5f * s;
  } else if (bx == 16) {
    // bicubic tap tables (f64, matches numpy)
    if (t >= 144) return;
    const int pns[9] = {1, 2, 3, 4, 5, 6, 8, 10, 13};
    int si = t / 16, Y = t % 16;
    int pn = pns[si];
    double src = (Y + 0.5) * (double)pn / 16.0 - 0.5;
    double fl = floor(src);
    const double a = -0.75;
#pragma unroll
    for (int k = 0; k < 4; ++k) {
      double x = fabs(src - (fl + (k - 1)));
      double w;
      if (x <= 1.0)      w = (a + 2.0) * x * x * x - (a + 3.0) * x * x + 1.0;
      else if (x < 2.0)  w = a * x * x * x - 5.0 * a * x * x + 8.0 * a * x - 4.0 * a;
      else               w = 0.0;
      int id = (int)fl + (k - 1);
      id = id < 0 ? 0 : (id > pn - 1 ? pn - 1 : id);
      tw[si * 64 + Y * 4 + k] = (float)w;
      ti[si * 64 + Y * 4 + k] = id;
    }
  } else if (bx < 33) {
    // phi weight split: wspl[phi][lvl][q][o][ci] bf16x3
    int i = (bx - 17) * 256 + t;   // 4096 (phi,o,ci)
    int phi = i >> 10, o = (i >> 5) & 31, ci = i & 31;
    const float* src = phiW + (((size_t)phi * 32 + o) * 32 + ci) * 9;
    ushort* dst = wspl + (size_t)phi * 27648;
#pragma unroll
    for (int q = 0; q < 9; ++q) {
      ushort uh, um, ul;
      split3(src[q], &uh, &um, &ul);
      dst[(size_t)(0 * 9 + q) * 1024 + o * 32 + ci] = uh;
      dst[(size_t)(9 + q) * 1024 + o * 32 + ci] = um;
      dst[(size_t)(18 + q) * 1024 + o * 32 + ci] = ul;
    }
  } else {
    // si=0 NN input: area-pool f to 1x1 -> [n][c] 3-level bf16
    int tid = (bx - 33) * 256 + t;   // 4096
    int c = tid & 31, n = tid >> 5;
    const float* base = f + ((size_t)n * 32 + c) * 256;
    float s = 0.f;
    for (int yy = 0; yy < 16; ++yy)
      for (int xx = 0; xx < 16; ++xx) s += base[yy * 16 + xx];
    float a = s * ((1.0f / 16.0f) * (1.0f / 16.0f));
    ushort uh, um, ul;
    split3(a, &uh, &um, &ul);
    rh[(size_t)n * 32 + c] = uh;
    rm[(size_t)n * 32 + c] = um;
    rl[(size_t)n * 32 + c] = ul;
  }
}

// --------------------------- NN search (unchanged round-4) ------------------
template<int R>
__global__ __launch_bounds__(256) void k_nn(const ushort* __restrict__ rest_h,
                                            const ushort* __restrict__ rest_m,
                                            const ushort* __restrict__ rest_l,
                                            const ushort* __restrict__ emb_h,
                                            const ushort* __restrict__ emb_m,
                                            const ushort* __restrict__ emb_l,
                                            const float* __restrict__ esq_g,
                                            float* __restrict__ pdist,
                                            int* __restrict__ pidx,
                                            int rows, int S, int cps) {
  __shared__ ushort lb[3][3][2048];
  __shared__ float les[3][64];
  const int t = threadIdx.x;
  const int w = t >> 6;
  const int col = t & 15;
  const int g = (t >> 4) & 3;
  const int sp = blockIdx.y;
  const int rowbase = blockIdx.x * (64 * R);

  auto stage = [&](int bf, int ch) {
    int cb = sp * cps + ch * 64;
    int code = cb + (t >> 2);
    int u = (t & 3) ^ ((code ^ (code >> 2)) & 3);
    size_t off = (size_t)code * 32 + (size_t)u * 8;
    gl_lds16(emb_h + off, &lb[bf][0][w * 512]);
    gl_lds16(emb_m + off, &lb[bf][1][w * 512]);
    gl_lds16(emb_l + off, &lb[bf][2][w * 512]);
    if ((t & 63) < 16) gl_lds4(esq_g + cb + w * 16 + (t & 15), &les[bf][w * 16]);
  };

  const int NC = cps >> 6;
  stage(0, 0);

  short8_t ah[R], am[R], al[R];
#pragma unroll
  for (int rt = 0; rt < R; ++rt) {
    int n = rowbase + (w * R + rt) * 16 + col;
    if (n >= rows) n = rows - 1;
    size_t o = (size_t)n * 32 + g * 8;
    ah[rt] = *(const short8_t*)(rest_h + o);
    am[rt] = *(const short8_t*)(rest_m + o);
    al[rt] = *(const short8_t*)(rest_l + o);
  }

  if (NC > 1) stage(1, 1);

  float best[R][4];
  int bidx[R][4];
#pragma unroll
  for (int rt = 0; rt < R; ++rt)
#pragma unroll
    for (int r = 0; r < 4; ++r) { best[rt][r] = -3.4e38f; bidx[rt][r] = 0x7fffffff; }

  int buf = 0;
  for (int ch = 0; ch < NC; ++ch) {
    if (ch + 2 < NC) {
      stage((ch + 2) % 3, ch + 2);
      asm volatile("s_waitcnt vmcnt(8)" ::: "memory");
    } else if (ch + 1 < NC) {
      asm volatile("s_waitcnt vmcnt(4)" ::: "memory");
    } else {
      asm volatile("s_waitcnt vmcnt(0)" ::: "memory");
    }
    __builtin_amdgcn_s_barrier();

    int cb0 = sp * cps + ch * 64;
#pragma unroll
    for (int s4 = 0; s4 < 4; ++s4) {
      int cl = s4 * 16 + col;
      int slotbase = (cl * 4 + (g ^ ((cl ^ (cl >> 2)) & 3))) * 8;
      short8_t bh  = *(const short8_t*)&lb[buf][0][slotbase];
      short8_t bm  = *(const short8_t*)&lb[buf][1][slotbase];
      short8_t bl2 = *(const short8_t*)&lb[buf][2][slotbase];
      float es = les[buf][cl];
      f32x4 c0 = {es, es, es, es};
      f32x4 acc[R];
#pragma unroll
      for (int rt = 0; rt < R; ++rt) acc[rt] = MFMA(ah[rt], bh, c0);
#pragma unroll
      for (int rt = 0; rt < R; ++rt) acc[rt] = MFMA(ah[rt], bm, acc[rt]);
#pragma unroll
      for (int rt = 0; rt < R; ++rt) acc[rt] = MFMA(am[rt], bh, acc[rt]);
#pragma unroll
      for (int rt = 0; rt < R; ++rt) acc[rt] = MFMA(ah[rt], bl2, acc[rt]);
#pragma unroll
      for (int rt = 0; rt < R; ++rt) acc[rt] = MFMA(am[rt], bm, acc[rt]);
#pragma unroll
      for (int rt = 0; rt < R; ++rt) acc[rt] = MFMA(al[rt], bh, acc[rt]);
      int code = cb0 + cl;
#pragma unroll
      for (int rt = 0; rt < R; ++rt)
#pragma unroll
        for (int r = 0; r < 4; ++r)
          if (acc[rt][r] > best[rt][r]) { best[rt][r] = acc[rt][r]; bidx[rt][r] = code; }
    }
    __syncthreads();
    buf = (buf + 1) % 3;
  }

#pragma unroll
  for (int rt = 0; rt < R; ++rt)
#pragma unroll
    for (int r = 0; r < 4; ++r) {
      float bd = best[rt][r];
      int bi = bidx[rt][r];
#pragma unroll
      for (int mm2 = 1; mm2 < 16; mm2 <<= 1) {
        float od = __shfl_xor(bd, mm2, 16);
        int oi = __shfl_xor(bi, mm2, 16);
        if (od > bd || (od == bd && oi < bi)) { bd = od; bi = oi; }
      }
      if ((t & 15) == 0) {
        int rown = rowbase + (w * R + rt) * 16 + g * 4 + r;
        if (rown < rows) {
          pdist[(size_t)rown * S + sp] = bd;
          pidx[(size_t)rown * S + sp] = bi;
        }
      }
    }
}

// --------------------------- fused per-scale kernel -------------------------
// grid (B,2), 512 thr, 16 out-ch per block. combine -> gather -> bicubic ->
// MFMA conv (9 shift-GEMMs, 3-level split) -> f_rest RMW + loss -> pool.
template<bool LAST>
__global__ __launch_bounds__(512) void k_scale(const float* __restrict__ pdist,
                                               const int* __restrict__ pidx,
                                               const float* __restrict__ emb,
                                               const float* __restrict__ tw,
                                               const int* __restrict__ ti,
                                               const ushort* __restrict__ wspl,
                                               const float* __restrict__ bias,
                                               const float* __restrict__ f,
                                               const float* __restrict__ fr_in,
                                               float* __restrict__ fr_out,
                                               float* __restrict__ fhat_out,
                                               float* __restrict__ out_idx_f,
                                               float* __restrict__ lossp,
                                               ushort* __restrict__ rh,
                                               ushort* __restrict__ rm,
                                               ushort* __restrict__ rl,
                                               int S, int pn, int si, int pn_next) {
  __shared__ ushort h_bf[3][256][40];   // 61440 B; hsm [32][176] aliased on top
  __shared__ float xt[32][208];         // 26624 B; pool-buf [16][256] aliased
  __shared__ float h_my[16][260];       // 16640 B
  __shared__ int ci_s[256];
  __shared__ float redw[8];
  float* hsm = (float*)&h_bf[0][0][0];
  float* poolb = &xt[0][0];

  const int b = blockIdx.x;
  const int cog = blockIdx.y * 16;
  const int t = threadIdx.x;
  const int pn2 = pn * pn;

  // ---- 1. combine split partials -> codes (+ idx output)
  for (int rem = t; rem < pn2; rem += 512) {
    const float* pd = pdist + (size_t)(b * pn2 + rem) * S;
    const int* pi = pidx + (size_t)(b * pn2 + rem) * S;
    float bd = pd[0]; int bi = pi[0];
    for (int s = 1; s < S; ++s) {
      float d = pd[s]; int i2 = pi[s];
      if (d > bd || (d == bd && i2 < bi)) { bd = d; bi = i2; }
    }
    ci_s[rem] = bi;
    out_idx_f[b * pn2 + rem] = (float)bi;
  }
  __syncthreads();

  // ---- 2-4. build h (f32 for my 16 ch, bf16x3 for all 32 ch)
  if (LAST) {
    for (int i = t; i < 8192; i += 512) {
      int pix = i & 255, c = i >> 8;
      float v = emb[(size_t)ci_s[pix] * 32 + c];
      ushort uh, um, ul; split3(v, &uh, &um, &ul);
      h_bf[0][pix][c] = uh; h_bf[1][pix][c] = um; h_bf[2][pix][c] = ul;
      int cl = c - cog;
      if ((unsigned)cl < 16u) h_my[cl][pix] = v;
    }
  } else {
    for (int i = t; i < 32 * pn2; i += 512) {
      int c = i & 31, rem = i >> 5;
      hsm[c * 176 + rem] = emb[(size_t)ci_s[rem] * 32 + c];
    }
    __syncthreads();
    // stage-1 x-interp -> xt[c][y*16+X]
    int e1 = 32 * pn * 16;
    for (int i = t; i < e1; i += 512) {
      int X = i & 15, r2 = i >> 4;
      int y = r2 % pn, c = r2 / pn;
      float a = 0.f;
#pragma unroll
      for (int u = 0; u < 4; ++u)
        a += tw[si * 64 + X * 4 + u] * hsm[c * 176 + y * pn + ti[si * 64 + X * 4 + u]];
      xt[c][y * 16 + X] = a;
    }
    __syncthreads();
    // stage-2 y-interp -> h_bf (overwrites hsm region; hsm dead) + h_my
    for (int i = t; i < 8192; i += 512) {
      int pix = i & 255, c = i >> 8;
      int X = pix & 15, Y = pix >> 4;
      float a = 0.f;
#pragma unroll
      for (int u = 0; u < 4; ++u)
        a += tw[si * 64 + Y * 4 + u] * xt[c][ti[si * 64 + Y * 4 + u] * 16 + X];
      ushort uh, um, ul; split3(a, &uh, &um, &ul);
      h_bf[0][pix][c] = uh; h_bf[1][pix][c] = um; h_bf[2][pix][c] = ul;
      int cl = c - cog;
      if ((unsigned)cl < 16u) h_my[cl][pix] = a;
    }
  }
  __syncthreads();

  // ---- 5. conv via MFMA. wave w owns image rows {2w, 2w+1}.
  const int w = t >> 6, l = t & 63;
  const int X = l & 15, kq = l >> 4;

  // prefetch f_rest (+f) RMW operands — latency hides under MFMAs
  float fr_old[2][4], f_old[2][4];
#pragma unroll
  for (int rr = 0; rr < 2; ++rr) {
    int pix = (w * 2 + rr) * 16 + X;
#pragma unroll
    for (int r = 0; r < 4; ++r) {
      size_t ga = ((size_t)b * 32 + cog + kq * 4 + r) * 256 + pix;
      fr_old[rr][r] = fr_in[ga];
      f_old[rr][r] = LAST ? f[ga] : 0.f;
    }
  }

  f32x4 accA[2], accB[2];
#pragma unroll
  for (int r = 0; r < 4; ++r) {
    float bv = bias[cog + kq * 4 + r];
    accA[0][r] = bv; accA[1][r] = bv;
    accB[0][r] = 0.f; accB[1][r] = 0.f;
  }

  for (int dy = 0; dy < 3; ++dy) {
    short8_t bc[2][3];
    bool ok0, ok1;
    {
      int Yp = w * 2 + 0 + dy - 1;
      ok0 = (Yp >= 0 && Yp < 16);
      if (ok0) {
#pragma unroll
        for (int lv = 0; lv < 3; ++lv)
          bc[0][lv] = *(const short8_t*)&h_bf[lv][Yp * 16 + X][kq * 8];
      }
    }
    {
      int Yp = w * 2 + 1 + dy - 1;
      ok1 = (Yp >= 0 && Yp < 16);
      if (ok1) {
#pragma unroll
        for (int lv = 0; lv < 3; ++lv)
          bc[1][lv] = *(const short8_t*)&h_bf[lv][Yp * 16 + X][kq * 8];
      }
    }
#pragma unroll
    for (int dx = 0; dx < 3; ++dx) {
      int q = dy * 3 + dx;
      const ushort* wp = wspl + (size_t)q * 1024 + (size_t)(cog + (l & 15)) * 32 + kq * 8;
      short8_t aH = *(const short8_t*)(wp);
      short8_t aM = *(const short8_t*)(wp + 9 * 1024);
      short8_t aL = *(const short8_t*)(wp + 18 * 1024);
#pragma unroll
      for (int rr = 0; rr < 2; ++rr) {
        bool ok = rr ? ok1 : ok0;
        if (!ok) continue;
        short8_t bH = bc[rr][0], bM = bc[rr][1], bL = bc[rr][2];
        if (dx == 0) { bH = s8_from_laneM1(bH); bM = s8_from_laneM1(bM); bL = s8_from_laneM1(bL); }
        else if (dx == 2) { bH = s8_from_laneP1(bH); bM = s8_from_laneP1(bM); bL = s8_from_laneP1(bL); }
        accA[rr] = MFMA(aH, bH, accA[rr]);
        accB[rr] = MFMA(aH, bM, accB[rr]);
        accA[rr] = MFMA(aM, bH, accA[rr]);
        accB[rr] = MFMA(aH, bL, accB[rr]);
        accA[rr] = MFMA(aM, bM, accA[rr]);
        accB[rr] = MFMA(aL, bH, accB[rr]);
      }
    }
  }

  // ---- 6. epilogue: residual mix, f_rest RMW, loss, pool staging
  float lsum = 0.f;
#pragma unroll
  for (int rr = 0; rr < 2; ++rr) {
    int pix = (w * 2 + rr) * 16 + X;
#pragma unroll
    for (int r = 0; r < 4; ++r) {
      int ol = kq * 4 + r;
      float convv = accA[rr][r] + accB[rr][r];
      float outv = 0.5f * h_my[ol][pix] + 0.5f * convv;
      float nf = fr_old[rr][r] - outv;
      size_t ga = ((size_t)b * 32 + cog + ol) * 256 + pix;
      if (LAST) {
        fhat_out[ga] = f_old[rr][r] - nf;
      } else {
        fr_out[ga] = nf;
        poolb[ol * 256 + pix] = nf;
      }
      lsum += nf * nf;
    }
  }

  // ---- 7. pool updated residual for next scale's NN input
  if (!LAST) {
    __syncthreads();
    int pn2n = pn_next * pn_next;
    for (int i = t; i < 16 * pn2n; i += 512) {
      int o = i / pn2n, rem = i - o * pn2n;
      int y = rem / pn_next, x = rem - y * pn_next;
      int sy = (y * 16) / pn_next, ey = ((y + 1) * 16 + pn_next - 1) / pn_next;
      int sx = (x * 16) / pn_next, ex = ((x + 1) * 16 + pn_next - 1) / pn_next;
      float s = 0.f;
      for (int yy = sy; yy < ey; ++yy)
        for (int xx = sx; xx < ex; ++xx) s += poolb[o * 256 + yy * 16 + xx];
      float a = s * ((1.0f / (float)(ey - sy)) * (1.0f / (float)(ex - sx)));
      ushort uh, um, ul;
      split3(a, &uh, &um, &ul);
      size_t n = (size_t)b * pn2n + rem;
      rh[n * 32 + cog + o] = uh;
      rm[n * 32 + cog + o] = um;
      rl[n * 32 + cog + o] = ul;
    }
  }

  // ---- 8. loss partial
#pragma unroll
  for (int off = 32; off > 0; off >>= 1) lsum += __shfl_down(lsum, off);
  if (l == 0) redw[w] = lsum;
  __syncthreads();
  if (t == 0) {
    float s2 = 0.f;
#pragma unroll
    for (int i = 0; i < 8; ++i) s2 += redw[i];
    lossp[si * 256 + blockIdx.y * 128 + b] = s2;
  }
}

__global__ __launch_bounds__(256) void k_lossfin(const float* __restrict__ part,
                                                 float* __restrict__ out) {
  int t = threadIdx.x;
  float s = 0.f;
  for (int i = t; i < SN_ * 256; i += 256) s += part[i];
  __shared__ float red[256];
  red[t] = s;
  __syncthreads();
  for (int o = 128; o > 0; o >>= 1) {
    if (t < o) red[t] += red[t + o];
    __syncthreads();
  }
  if (t == 0) out[NPIX_] = red[0] * (1.25f / (10.0f * (float)NPIX_));
}

// --------------------------- host side -------------------------------------

static void compute_phi_k(int* ks) {
  const int K = 4;
  double start = 1.0 / (3.0 * K);
  double stop = 1.0 - 1.0 / (3.0 * K);
  double step = (stop - start) / (K - 1);
  double ticks[4];
  for (int i = 0; i < K; ++i) ticks[i] = (double)i * step + start;
  ticks[K - 1] = stop;
  for (int si = 0; si < SN_; ++si) {
    double x = (double)si / (SN_ - 1);
    int best = 0;
    double bd = fabs(ticks[0] - x);
    for (int i = 1; i < K; ++i) {
      double d = fabs(ticks[i] - x);
      if (d < bd) { bd = d; best = i; }
    }
    ks[si] = best;
  }
}

extern "C" void kernel_launch(void* const* d_in, const int* in_sizes, int n_in,
                              void* d_out, int out_size, void* d_ws, size_t ws_size,
                              hipStream_t stream) {
  (void)in_sizes; (void)n_in; (void)out_size; (void)ws_size;
  const float* f    = (const float*)d_in[0];
  const float* emb  = (const float*)d_in[1];
  const float* phiW = (const float*)d_in[2];
  const float* phiB = (const float*)d_in[3];
  float* out = (float*)d_out;
  float* ws = (float*)d_ws;

  float* f_rest = ws + WS_FREST;
  float* pdist  = ws + WS_PD;
  int*   pidx   = (int*)(ws + WS_PI);
  float* esq    = ws + WS_ESQ;
  float* tw     = ws + WS_TW;
  int*   ti     = (int*)(ws + WS_TI);
  float* lossp  = ws + WS_LOSSP;
  ushort* rest_h = (ushort*)(ws + WS_RESTH);
  ushort* rest_m = (ushort*)(ws + WS_RESTM);
  ushort* rest_l = (ushort*)(ws + WS_RESTL);
  ushort* emb_h  = (ushort*)(ws + WS_EMBH);
  ushort* emb_m  = (ushort*)(ws + WS_EMBM);
  ushort* emb_l  = (ushort*)(ws + WS_EMBL);
  ushort* wspl   = (ushort*)(ws + WS_WSPL);

  static const int pns[SN_] = {1, 2, 3, 4, 5, 6, 8, 10, 13, 16};
  static const int Rs[SN_]  = {1, 1, 1, 2, 2, 2, 4, 4, 4, 4};
  static const int Ss[SN_]  = {64, 64, 32, 32, 32, 16, 16, 16, 8, 8};
  int ks[SN_];
  compute_phi_k(ks);

  k_prep<<<49, 256, 0, stream>>>(emb, f, phiW, esq, emb_h, emb_m, emb_l, tw, ti,
                                 rest_h, rest_m, rest_l, wspl);

  int idx_off = 0;
  for (int si = 0; si < SN_; ++si) {
    int pn = pns[si];
    int pn2 = pn * pn;
    int rows = B_ * pn2;
    int R = Rs[si], S = Ss[si];
    int cps = V_ / S;
    int rowblocks = (rows + 64 * R - 1) / (64 * R);

    dim3 grid(rowblocks, S);
    if (R == 1)
      k_nn<1><<<grid, 256, 0, stream>>>(rest_h, rest_m, rest_l, emb_h, emb_m, emb_l,
                                        esq, pdist, pidx, rows, S, cps);
    else if (R == 2)
      k_nn<2><<<grid, 256, 0, stream>>>(rest_h, rest_m, rest_l, emb_h, emb_m, emb_l,
                                        esq, pdist, pidx, rows, S, cps);
    else
      k_nn<4><<<grid, 256, 0, stream>>>(rest_h, rest_m, rest_l, emb_h, emb_m, emb_l,
                                        esq, pdist, pidx, rows, S, cps);

    bool last = (si == SN_ - 1);
    int pn_next = last ? 0 : pns[si + 1];
    const ushort* wsp = wspl + (size_t)ks[si] * 27648;
    const float* bi = phiB + (size_t)ks[si] * 32;
    if (last)
      k_scale<true><<<dim3(B_, 2), 512, 0, stream>>>(
          pdist, pidx, emb, tw, ti, wsp, bi, f,
          f_rest, f_rest, out,
          out + NPIX_ + 1 + idx_off, lossp,
          rest_h, rest_m, rest_l, S, pn, si, pn_next);
    else
      k_scale<false><<<dim3(B_, 2), 512, 0, stream>>>(
          pdist, pidx, emb, tw, ti, wsp, bi, f,
          (si == 0) ? f : f_rest, f_rest, nullptr,
          out + NPIX_ + 1 + idx_off, lossp,
          rest_h, rest_m, rest_l, S, pn, si, pn_next);
    idx_off += rows;
  }

  k_lossfin<<<1, 256, 0, stream>>>(lossp, out);
}